// Round 5
// baseline (1738.187 us; speedup 1.0000x reference)
//
#include <hip/hip_runtime.h>
#include <hip/hip_bf16.h>

#define NN 50000
#define NE 800000
#define D 128
#define ED 64
#define IN_DIM 320
#define MB 64            // edges per tile
#define KP 328           // padded LDS row (ushorts)
#define NT (NE / MB)     // 12500 tiles
#define PGRID 512        // persistent grid: 2 blocks/CU * 256 CU

typedef short short8 __attribute__((ext_vector_type(8)));
typedef float f32x4 __attribute__((ext_vector_type(4)));

__device__ __forceinline__ ushort f2b(float f) {
  __hip_bfloat16 h = __float2bfloat16(f);
  return *reinterpret_cast<ushort*>(&h);
}
__device__ __forceinline__ float b2f(ushort u) {
  return __uint_as_float(((uint)u) << 16);
}
__device__ __forceinline__ ushort4 c4(float4 v) {
  ushort4 u; u.x = f2b(v.x); u.y = f2b(v.y); u.z = f2b(v.z); u.w = f2b(v.w);
  return u;
}

// gather one tile's x into bf16 registers; 4 threads per edge, 20 x ushort4
__device__ __forceinline__ void gather_regs(
    ushort4 g[20], const int* __restrict__ senders,
    const int* __restrict__ receivers, const float* __restrict__ nodes,
    const float* __restrict__ efeat, int e0, int tid)
{
  const int e = tid >> 2, p = tid & 3;
  const float* ns = nodes + (size_t)senders[e0 + e] * D;
  const float* nr = nodes + (size_t)receivers[e0 + e] * D;
  const float* ef = efeat + (size_t)(e0 + e) * ED;
#pragma unroll
  for (int i = 0; i < 8; ++i) g[i] = c4(*(const float4*)(ns + (p + 4 * i) * 4));
#pragma unroll
  for (int i = 0; i < 8; ++i) g[8 + i] = c4(*(const float4*)(nr + (p + 4 * i) * 4));
#pragma unroll
  for (int i = 0; i < 4; ++i) g[16 + i] = c4(*(const float4*)(ef + (p + 4 * i) * 4));
}

__device__ __forceinline__ void write_xs(
    ushort xs[MB][KP], const ushort4 g[20], int tid)
{
  const int e = tid >> 2, p = tid & 3;
#pragma unroll
  for (int i = 0; i < 8; ++i)
    *reinterpret_cast<ushort4*>(&xs[e][(p + 4 * i) * 4]) = g[i];
#pragma unroll
  for (int i = 0; i < 8; ++i)
    *reinterpret_cast<ushort4*>(&xs[e][128 + (p + 4 * i) * 4]) = g[8 + i];
#pragma unroll
  for (int i = 0; i < 4; ++i)
    *reinterpret_cast<ushort4*>(&xs[e][256 + (p + 4 * i) * 4]) = g[16 + i];
}

// ---------------- weight transpose + bf16 convert ---------------------------
__global__ __launch_bounds__(256) void k_wconv(
    const float* __restrict__ Wq, const float* __restrict__ W1,
    ushort* __restrict__ Wqt, ushort* __restrict__ W1t)
{
  int i = blockIdx.x * 256 + threadIdx.x;
  if (i < D * IN_DIM) {
    int n = i / IN_DIM, k = i - n * IN_DIM;
    Wqt[i] = f2b(Wq[k * D + n]);
    W1t[i] = f2b(W1[k * D + n]);
  }
}

// ======================= FUSED PATH =========================================
// pass 1: queries (bf16, +bq) + logits + segment max, persistent+prefetched
__global__ __launch_bounds__(256, 2) void k_fused(
    const float* __restrict__ nodes,
    const int* __restrict__ senders, const int* __restrict__ receivers,
    const float* __restrict__ efeat,
    const ushort* __restrict__ Wqt, const float* __restrict__ bq,
    const ushort* __restrict__ W1t, const float* __restrict__ b1,
    const float* __restrict__ gamma_, const float* __restrict__ beta_,
    const float* __restrict__ W2, const float* __restrict__ b2,
    ushort* __restrict__ queries, float* __restrict__ logits,
    float* __restrict__ seg_max)
{
  __shared__ ushort xs[MB][KP];
  __shared__ float red[MB][4][3];
  const int tid = threadIdx.x;
  const int w = tid >> 6, l = tid & 63, lr = l & 15, lg = l >> 4;
  const int n0 = 32 * w + lr, n1 = 32 * w + 16 + lr;

  const float b1a = b1[n0], b1b = b1[n1];
  const float g0 = gamma_[n0], g1 = gamma_[n1];
  const float be0 = beta_[n0], be1 = beta_[n1];
  const float w20 = W2[n0], w21 = W2[n1];
  const float bq0 = bq[n0], bq1 = bq[n1];
  const float b2s = b2[0];
  const float wg0 = w20 * g0, wg1 = w21 * g1;

  // W1 panel resident in registers for the whole kernel (no VMEM in h-GEMM)
  short8 B1r[10][2];
#pragma unroll
  for (int ks = 0; ks < 10; ++ks) {
    B1r[ks][0] = *reinterpret_cast<const short8*>(W1t + n0 * IN_DIM + ks * 32 + lg * 8);
    B1r[ks][1] = *reinterpret_cast<const short8*>(W1t + n1 * IN_DIM + ks * 32 + lg * 8);
  }

  // tile-invariant scalars: S1 = sum(w2*g), B2t = sum(w2*beta) + b2.
  // NOTE: the 64-lane reduce counts each column 4x (4 lg-groups share the
  // same n0/n1), hence the 0.25 factor. (Round-4 bug: missing 0.25.)
  {
    float p1 = wg0 + wg1;
    float p2 = w20 * be0 + w21 * be1;
#pragma unroll
    for (int off = 1; off < 64; off <<= 1) {
      p1 += __shfl_xor(p1, off);
      p2 += __shfl_xor(p2, off);
    }
    if (l == 0) { red[0][w][0] = p1; red[0][w][1] = p2; }
  }
  __syncthreads();
  const float S1  = 0.25f * (red[0][0][0] + red[0][1][0] + red[0][2][0] + red[0][3][0]);
  const float B2t = 0.25f * (red[0][0][1] + red[0][1][1] + red[0][2][1] + red[0][3][1]) + b2s;
  // (no extra sync needed: red is only rewritten after sync (A) below)

  int tile = blockIdx.x;
  ushort4 g[20];
  gather_regs(g, senders, receivers, nodes, efeat, tile * MB, tid);

  while (tile < NT) {
    const int e0 = tile * MB;
    write_xs(xs, g, tid);
    __syncthreads();                                   // (A) xs ready

    // ---- q-GEMM: Wq streamed from L2 (issued BEFORE prefetch gathers)
    f32x4 aq[4][2] = {};
#pragma unroll 2
    for (int ks = 0; ks < 10; ++ks) {
      short8 Q0 = *reinterpret_cast<const short8*>(Wqt + n0 * IN_DIM + ks * 32 + lg * 8);
      short8 Q1 = *reinterpret_cast<const short8*>(Wqt + n1 * IN_DIM + ks * 32 + lg * 8);
      short8 A[4];
#pragma unroll
      for (int mt = 0; mt < 4; ++mt)
        A[mt] = *reinterpret_cast<const short8*>(&xs[mt * 16 + lr][ks * 32 + lg * 8]);
#pragma unroll
      for (int mt = 0; mt < 4; ++mt) {
        aq[mt][0] = __builtin_amdgcn_mfma_f32_16x16x32_bf16(A[mt], Q0, aq[mt][0], 0, 0, 0);
        aq[mt][1] = __builtin_amdgcn_mfma_f32_16x16x32_bf16(A[mt], Q1, aq[mt][1], 0, 0, 0);
      }
    }
    // store queries (+bq) as bf16
#pragma unroll
    for (int mt = 0; mt < 4; ++mt)
#pragma unroll
      for (int r = 0; r < 4; ++r) {
        int row = mt * 16 + lg * 4 + r;
        queries[(size_t)(e0 + row) * D + n0] = f2b(aq[mt][0][r] + bq0);
        queries[(size_t)(e0 + row) * D + n1] = f2b(aq[mt][1][r] + bq1);
      }

    // ---- prefetch next tile's gathers (no VMEM loads after this point)
    const int nxt = tile + PGRID;
    if (nxt < NT)
      gather_regs(g, senders, receivers, nodes, efeat, nxt * MB, tid);

    // ---- h-GEMM: weights from registers, A from LDS — zero VMEM
    f32x4 ah[4][2] = {};
#pragma unroll
    for (int ks = 0; ks < 10; ++ks) {
      short8 A[4];
#pragma unroll
      for (int mt = 0; mt < 4; ++mt)
        A[mt] = *reinterpret_cast<const short8*>(&xs[mt * 16 + lr][ks * 32 + lg * 8]);
#pragma unroll
      for (int mt = 0; mt < 4; ++mt) {
        ah[mt][0] = __builtin_amdgcn_mfma_f32_16x16x32_bf16(A[mt], B1r[ks][0], ah[mt][0], 0, 0, 0);
        ah[mt][1] = __builtin_amdgcn_mfma_f32_16x16x32_bf16(A[mt], B1r[ks][1], ah[mt][1], 0, 0, 0);
      }
    }

    // relu + fused LN/dot partials: s, q, t = sum(w2*g*h) — 16-lane reduce,
    // each column counted exactly once per lg-group
#pragma unroll
    for (int mt = 0; mt < 4; ++mt)
#pragma unroll
      for (int r = 0; r < 4; ++r) {
        float h0 = fmaxf(ah[mt][0][r] + b1a, 0.f);
        float h1 = fmaxf(ah[mt][1][r] + b1b, 0.f);
        float s = h0 + h1;
        float q = h0 * h0 + h1 * h1;
        float t = h0 * wg0 + h1 * wg1;
#pragma unroll
        for (int off = 1; off < 16; off <<= 1) {
          s += __shfl_xor(s, off);
          q += __shfl_xor(q, off);
          t += __shfl_xor(t, off);
        }
        if (lr == mt * 4 + r) {
          int row = mt * 16 + lg * 4 + r;
          red[row][w][0] = s;
          red[row][w][1] = q;
          red[row][w][2] = t;
        }
      }
    __syncthreads();                                   // (B) red ready
    if (tid < MB) {
      float s = red[tid][0][0] + red[tid][1][0] + red[tid][2][0] + red[tid][3][0];
      float q = red[tid][0][1] + red[tid][1][1] + red[tid][2][1] + red[tid][3][1];
      float t = red[tid][0][2] + red[tid][1][2] + red[tid][2][2] + red[tid][3][2];
      float mu = s * (1.f / 128.f);
      float var = fmaxf(q * (1.f / 128.f) - mu * mu, 0.f);
      float rs = rsqrtf(var + 1e-5f);
      float logit = fmaxf(rs * (t - mu * S1) + B2t, 0.f);
      logits[e0 + tid] = logit;
      atomicMax((int*)&seg_max[receivers[e0 + tid]], __float_as_int(logit));
    }
    tile = nxt;
  }
}

// pass 3 (fused path): read queries, weight, atomic scatter
__global__ __launch_bounds__(256) void k_qscatter(
    const ushort* __restrict__ queries, const int* __restrict__ receivers,
    const float* __restrict__ exp_l, const float* __restrict__ seg_sum,
    float* __restrict__ accum)
{
  size_t gid = (size_t)blockIdx.x * 256 + threadIdx.x;   // NE*32 threads
  int e = (int)(gid >> 5), cg = ((int)gid & 31) * 4;
  int r = receivers[e];
  float wt = exp_l[e] / (seg_sum[r] + 1e-10f);
  ushort4 q = *reinterpret_cast<const ushort4*>(queries + (size_t)e * D + cg);
  float* dst = accum + (size_t)r * D + cg;
  atomicAdd(dst + 0, b2f(q.x) * wt);
  atomicAdd(dst + 1, b2f(q.y) * wt);
  atomicAdd(dst + 2, b2f(q.z) * wt);
  atomicAdd(dst + 3, b2f(q.w) * wt);
}

// ======================= FALLBACK PATH (round-2, known-good) ================
__device__ __forceinline__ void stage_x_sep(
    ushort xs[MB][KP], const int* __restrict__ senders,
    const int* __restrict__ receivers, const float* __restrict__ nodes,
    const float* __restrict__ efeat, int e0, int tid)
{
  ushort4 g[20];
  gather_regs(g, senders, receivers, nodes, efeat, e0, tid);
  write_xs(xs, g, tid);
}

__global__ __launch_bounds__(256) void k_logits_sep(
    const float* __restrict__ nodes,
    const int* __restrict__ senders, const int* __restrict__ receivers,
    const float* __restrict__ efeat,
    const ushort* __restrict__ W1t, const float* __restrict__ b1,
    const float* __restrict__ gamma_, const float* __restrict__ beta_,
    const float* __restrict__ W2, const float* __restrict__ b2,
    float* __restrict__ logits, float* __restrict__ seg_max)
{
  __shared__ ushort xs[MB][KP];
  __shared__ int sR[MB];
  __shared__ float red[MB][4][2];
  __shared__ float fin[MB][2];
  __shared__ float dred[MB][4];
  const int tid = threadIdx.x;
  const int e0 = blockIdx.x * MB;
  if (tid < MB) sR[tid] = receivers[e0 + tid];
  stage_x_sep(xs, senders, receivers, nodes, efeat, e0, tid);
  const int w = tid >> 6, l = tid & 63, lr = l & 15, lg = l >> 4;
  const int n0 = 32 * w + lr, n1 = 32 * w + 16 + lr;
  short8 Bf[10][2];
#pragma unroll
  for (int ks = 0; ks < 10; ++ks) {
    Bf[ks][0] = *reinterpret_cast<const short8*>(W1t + n0 * IN_DIM + ks * 32 + lg * 8);
    Bf[ks][1] = *reinterpret_cast<const short8*>(W1t + n1 * IN_DIM + ks * 32 + lg * 8);
  }
  __syncthreads();
  f32x4 acc[4][2] = {};
#pragma unroll
  for (int ks = 0; ks < 10; ++ks) {
    short8 A[4];
#pragma unroll
    for (int mt = 0; mt < 4; ++mt)
      A[mt] = *reinterpret_cast<const short8*>(&xs[mt * 16 + lr][ks * 32 + lg * 8]);
#pragma unroll
    for (int mt = 0; mt < 4; ++mt) {
      acc[mt][0] = __builtin_amdgcn_mfma_f32_16x16x32_bf16(A[mt], Bf[ks][0], acc[mt][0], 0, 0, 0);
      acc[mt][1] = __builtin_amdgcn_mfma_f32_16x16x32_bf16(A[mt], Bf[ks][1], acc[mt][1], 0, 0, 0);
    }
  }
  const float b1a = b1[n0], b1b = b1[n1];
#pragma unroll
  for (int mt = 0; mt < 4; ++mt)
#pragma unroll
    for (int r = 0; r < 4; ++r) {
      acc[mt][0][r] = fmaxf(acc[mt][0][r] + b1a, 0.f);
      acc[mt][1][r] = fmaxf(acc[mt][1][r] + b1b, 0.f);
    }
#pragma unroll
  for (int mt = 0; mt < 4; ++mt)
#pragma unroll
    for (int r = 0; r < 4; ++r) {
      float s = acc[mt][0][r] + acc[mt][1][r];
      float q = acc[mt][0][r] * acc[mt][0][r] + acc[mt][1][r] * acc[mt][1][r];
#pragma unroll
      for (int off = 1; off < 16; off <<= 1) {
        s += __shfl_xor(s, off);
        q += __shfl_xor(q, off);
      }
      if (lr == mt * 4 + r) {
        red[mt * 16 + lg * 4 + r][w][0] = s;
        red[mt * 16 + lg * 4 + r][w][1] = q;
      }
    }
  __syncthreads();
  if (tid < MB) {
    float s = red[tid][0][0] + red[tid][1][0] + red[tid][2][0] + red[tid][3][0];
    float q = red[tid][0][1] + red[tid][1][1] + red[tid][2][1] + red[tid][3][1];
    float mu = s * (1.f / 128.f);
    float var = fmaxf(q * (1.f / 128.f) - mu * mu, 0.f);
    fin[tid][0] = mu;
    fin[tid][1] = rsqrtf(var + 1e-5f);
  }
  __syncthreads();
  const float g0 = gamma_[n0], g1 = gamma_[n1];
  const float be0 = beta_[n0], be1 = beta_[n1];
  const float w20 = W2[n0], w21 = W2[n1];
#pragma unroll
  for (int mt = 0; mt < 4; ++mt)
#pragma unroll
    for (int r = 0; r < 4; ++r) {
      int row = mt * 16 + lg * 4 + r;
      float mu = fin[row][0], rs = fin[row][1];
      float h0 = (acc[mt][0][r] - mu) * rs * g0 + be0;
      float h1 = (acc[mt][1][r] - mu) * rs * g1 + be1;
      float dv = h0 * w20 + h1 * w21;
#pragma unroll
      for (int off = 1; off < 16; off <<= 1) dv += __shfl_xor(dv, off);
      if (lr == mt * 4 + r) dred[row][w] = dv;
    }
  __syncthreads();
  if (tid < MB) {
    float dv = dred[tid][0] + dred[tid][1] + dred[tid][2] + dred[tid][3] + b2[0];
    float logit = fmaxf(dv, 0.f);
    logits[e0 + tid] = logit;
    atomicMax((int*)&seg_max[sR[tid]], __float_as_int(logit));
  }
}

__global__ __launch_bounds__(256) void k_scatter_sep(
    const float* __restrict__ nodes,
    const int* __restrict__ senders, const int* __restrict__ receivers,
    const float* __restrict__ efeat,
    const ushort* __restrict__ Wqt, const float* __restrict__ bq,
    const float* __restrict__ exp_l, const float* __restrict__ seg_sum,
    float* __restrict__ accum)
{
  __shared__ ushort xs[MB][KP];
  __shared__ float wrow[MB];
  __shared__ int rr[MB];
  const int tid = threadIdx.x;
  const int e0 = blockIdx.x * MB;
  if (tid < MB) {
    int r = receivers[e0 + tid];
    rr[tid] = r;
    wrow[tid] = exp_l[e0 + tid] / (seg_sum[r] + 1e-10f);
  }
  stage_x_sep(xs, senders, receivers, nodes, efeat, e0, tid);
  const int w = tid >> 6, l = tid & 63, lr = l & 15, lg = l >> 4;
  const int n0 = 32 * w + lr, n1 = 32 * w + 16 + lr;
  short8 Bf[10][2];
#pragma unroll
  for (int ks = 0; ks < 10; ++ks) {
    Bf[ks][0] = *reinterpret_cast<const short8*>(Wqt + n0 * IN_DIM + ks * 32 + lg * 8);
    Bf[ks][1] = *reinterpret_cast<const short8*>(Wqt + n1 * IN_DIM + ks * 32 + lg * 8);
  }
  __syncthreads();
  f32x4 acc[4][2] = {};
#pragma unroll
  for (int ks = 0; ks < 10; ++ks) {
    short8 A[4];
#pragma unroll
    for (int mt = 0; mt < 4; ++mt)
      A[mt] = *reinterpret_cast<const short8*>(&xs[mt * 16 + lr][ks * 32 + lg * 8]);
#pragma unroll
    for (int mt = 0; mt < 4; ++mt) {
      acc[mt][0] = __builtin_amdgcn_mfma_f32_16x16x32_bf16(A[mt], Bf[ks][0], acc[mt][0], 0, 0, 0);
      acc[mt][1] = __builtin_amdgcn_mfma_f32_16x16x32_bf16(A[mt], Bf[ks][1], acc[mt][1], 0, 0, 0);
    }
  }
  const float bq0 = bq[n0], bq1 = bq[n1];
#pragma unroll
  for (int mt = 0; mt < 4; ++mt)
#pragma unroll
    for (int r = 0; r < 4; ++r) {
      int row = mt * 16 + lg * 4 + r;
      float wt_ = wrow[row];
      size_t base = (size_t)rr[row] * D;
      atomicAdd(&accum[base + n0], (acc[mt][0][r] + bq0) * wt_);
      atomicAdd(&accum[base + n1], (acc[mt][1][r] + bq1) * wt_);
    }
}

// ---------------- shared small kernels --------------------------------------
__global__ __launch_bounds__(256) void k_exp(
    const float* __restrict__ logits, const int* __restrict__ receivers,
    const float* __restrict__ seg_max, float* __restrict__ exp_l,
    float* __restrict__ seg_sum)
{
  int i = blockIdx.x * 256 + threadIdx.x;
  if (i < NE) {
    int r = receivers[i];
    float ex = expf(logits[i] - seg_max[r]);
    exp_l[i] = ex;
    atomicAdd(&seg_sum[r], ex);
  }
}

__global__ __launch_bounds__(256) void k_final(
    const float* __restrict__ accum, float* __restrict__ out)
{
  int i = blockIdx.x * 256 + threadIdx.x;
  if (i < NN * D) {
    float v = accum[i];
    out[i] = v > 0.f ? v : 0.01f * v;
  }
}

extern "C" void kernel_launch(void* const* d_in, const int* in_sizes, int n_in,
                              void* d_out, int out_size, void* d_ws, size_t ws_size,
                              hipStream_t stream) {
  const float* nodes  = (const float*)d_in[0];
  const int*   eidx   = (const int*)d_in[1];
  const float* efeat  = (const float*)d_in[2];
  const float* Wq     = (const float*)d_in[3];
  const float* bq     = (const float*)d_in[4];
  const float* W1     = (const float*)d_in[5];
  const float* b1     = (const float*)d_in[6];
  const float* gamma_ = (const float*)d_in[7];
  const float* beta_  = (const float*)d_in[8];
  const float* W2     = (const float*)d_in[9];
  const float* b2     = (const float*)d_in[10];
  const int* senders   = eidx;
  const int* receivers = eidx + NE;

  float* ws      = (float*)d_ws;
  float* logits  = ws;                  // NE
  float* exp_l   = ws + NE;             // NE
  float* seg_max = ws + 2 * NE;         // NN
  float* seg_sum = seg_max + NN;        // NN
  float* accum   = seg_sum + NN;        // NN*D
  ushort* Wqt    = (ushort*)(accum + (size_t)NN * D);  // 128*320
  ushort* W1t    = Wqt + D * IN_DIM;                   // 128*320
  ushort* queries = W1t + D * IN_DIM;                  // NE*128 bf16

  const size_t base_need = ((size_t)2 * NE + 2 * NN + (size_t)NN * D) * 4
                           + (size_t)2 * D * IN_DIM * 2;
  const size_t fused_need = base_need + (size_t)NE * D * 2;

  hipMemsetAsync(seg_max, 0, NN * sizeof(float), stream);
  hipMemsetAsync(seg_sum, 0, NN * sizeof(float), stream);
  hipMemsetAsync(accum, 0, (size_t)NN * D * sizeof(float), stream);

  k_wconv<<<(D * IN_DIM + 255) / 256, 256, 0, stream>>>(Wq, W1, Wqt, W1t);

  if (ws_size >= fused_need) {
    k_fused<<<PGRID, 256, 0, stream>>>(nodes, senders, receivers, efeat,
                                       Wqt, bq, W1t, b1, gamma_, beta_, W2, b2,
                                       queries, logits, seg_max);
    k_exp<<<(NE + 255) / 256, 256, 0, stream>>>(logits, receivers, seg_max,
                                                exp_l, seg_sum);
    k_qscatter<<<(int)(((size_t)NE * 32) / 256), 256, 0, stream>>>(
        queries, receivers, exp_l, seg_sum, accum);
  } else {
    k_logits_sep<<<NE / MB, 256, 0, stream>>>(nodes, senders, receivers, efeat,
                                              W1t, b1, gamma_, beta_, W2, b2,
                                              logits, seg_max);
    k_exp<<<(NE + 255) / 256, 256, 0, stream>>>(logits, receivers, seg_max,
                                                exp_l, seg_sum);
    k_scatter_sep<<<NE / MB, 256, 0, stream>>>(nodes, senders, receivers, efeat,
                                               Wqt, bq, exp_l, seg_sum, accum);
  }
  k_final<<<(NN * D + 255) / 256, 256, 0, stream>>>(accum, (float*)d_out);
}

// Round 6
// 552.714 us; speedup vs baseline: 3.1448x; 3.1448x over previous
//
#include <hip/hip_runtime.h>
#include <hip/hip_bf16.h>

#define NN 50000
#define NE 800000
#define D 128
#define ED 64
#define IN_DIM 320
#define MB 64            // edges per tile
#define KP 328           // padded LDS row (ushorts)
#define NT (NE / MB)     // 12500 tiles
#define PGRID 512        // persistent grid: 2 blocks/CU * 256 CU
#define NB ((NN + 255) / 256)   // 196 scan blocks

typedef short short8 __attribute__((ext_vector_type(8)));
typedef float f32x4 __attribute__((ext_vector_type(4)));

__device__ __forceinline__ ushort f2b(float f) {
  __hip_bfloat16 h = __float2bfloat16(f);
  return *reinterpret_cast<ushort*>(&h);
}
__device__ __forceinline__ float b2f(ushort u) {
  return __uint_as_float(((uint)u) << 16);
}
__device__ __forceinline__ ushort4 c4(float4 v) {
  ushort4 u; u.x = f2b(v.x); u.y = f2b(v.y); u.z = f2b(v.z); u.w = f2b(v.w);
  return u;
}

// gather one tile's x into bf16 registers; 4 threads per edge, 20 x ushort4
__device__ __forceinline__ void gather_regs(
    ushort4 g[20], const int* __restrict__ senders,
    const int* __restrict__ receivers, const float* __restrict__ nodes,
    const float* __restrict__ efeat, int e0, int tid)
{
  const int e = tid >> 2, p = tid & 3;
  const float* ns = nodes + (size_t)senders[e0 + e] * D;
  const float* nr = nodes + (size_t)receivers[e0 + e] * D;
  const float* ef = efeat + (size_t)(e0 + e) * ED;
#pragma unroll
  for (int i = 0; i < 8; ++i) g[i] = c4(*(const float4*)(ns + (p + 4 * i) * 4));
#pragma unroll
  for (int i = 0; i < 8; ++i) g[8 + i] = c4(*(const float4*)(nr + (p + 4 * i) * 4));
#pragma unroll
  for (int i = 0; i < 4; ++i) g[16 + i] = c4(*(const float4*)(ef + (p + 4 * i) * 4));
}

__device__ __forceinline__ void write_xs(
    ushort xs[MB][KP], const ushort4 g[20], int tid)
{
  const int e = tid >> 2, p = tid & 3;
#pragma unroll
  for (int i = 0; i < 8; ++i)
    *reinterpret_cast<ushort4*>(&xs[e][(p + 4 * i) * 4]) = g[i];
#pragma unroll
  for (int i = 0; i < 8; ++i)
    *reinterpret_cast<ushort4*>(&xs[e][128 + (p + 4 * i) * 4]) = g[8 + i];
#pragma unroll
  for (int i = 0; i < 4; ++i)
    *reinterpret_cast<ushort4*>(&xs[e][256 + (p + 4 * i) * 4]) = g[16 + i];
}

// ---------------- weight transpose + bf16 convert ---------------------------
__global__ __launch_bounds__(256) void k_wconv(
    const float* __restrict__ Wq, const float* __restrict__ W1,
    ushort* __restrict__ Wqt, ushort* __restrict__ W1t)
{
  int i = blockIdx.x * 256 + threadIdx.x;
  if (i < D * IN_DIM) {
    int n = i / IN_DIM, k = i - n * IN_DIM;
    Wqt[i] = f2b(Wq[k * D + n]);
    W1t[i] = f2b(W1[k * D + n]);
  }
}

// ---------------- pass 1: queries (bf16,+bq) + logits + seg_max -------------
__global__ __launch_bounds__(256, 2) void k_fused(
    const float* __restrict__ nodes,
    const int* __restrict__ senders, const int* __restrict__ receivers,
    const float* __restrict__ efeat,
    const ushort* __restrict__ Wqt, const float* __restrict__ bq,
    const ushort* __restrict__ W1t, const float* __restrict__ b1,
    const float* __restrict__ gamma_, const float* __restrict__ beta_,
    const float* __restrict__ W2, const float* __restrict__ b2,
    ushort* __restrict__ queries, float* __restrict__ logits,
    float* __restrict__ seg_max)
{
  __shared__ ushort xs[MB][KP];
  __shared__ float red[MB][4][3];
  const int tid = threadIdx.x;
  const int w = tid >> 6, l = tid & 63, lr = l & 15, lg = l >> 4;
  const int n0 = 32 * w + lr, n1 = 32 * w + 16 + lr;

  const float b1a = b1[n0], b1b = b1[n1];
  const float g0 = gamma_[n0], g1 = gamma_[n1];
  const float be0 = beta_[n0], be1 = beta_[n1];
  const float w20 = W2[n0], w21 = W2[n1];
  const float bq0 = bq[n0], bq1 = bq[n1];
  const float b2s = b2[0];
  const float wg0 = w20 * g0, wg1 = w21 * g1;

  // W1 panel resident in registers for the whole kernel
  short8 B1r[10][2];
#pragma unroll
  for (int ks = 0; ks < 10; ++ks) {
    B1r[ks][0] = *reinterpret_cast<const short8*>(W1t + n0 * IN_DIM + ks * 32 + lg * 8);
    B1r[ks][1] = *reinterpret_cast<const short8*>(W1t + n1 * IN_DIM + ks * 32 + lg * 8);
  }

  // tile-invariant: S1=sum(w2*g), B2t=sum(w2*beta)+b2 (0.25: cols counted 4x)
  {
    float p1 = wg0 + wg1;
    float p2 = w20 * be0 + w21 * be1;
#pragma unroll
    for (int off = 1; off < 64; off <<= 1) {
      p1 += __shfl_xor(p1, off);
      p2 += __shfl_xor(p2, off);
    }
    if (l == 0) { red[0][w][0] = p1; red[0][w][1] = p2; }
  }
  __syncthreads();
  const float S1  = 0.25f * (red[0][0][0] + red[0][1][0] + red[0][2][0] + red[0][3][0]);
  const float B2t = 0.25f * (red[0][0][1] + red[0][1][1] + red[0][2][1] + red[0][3][1]) + b2s;

  int tile = blockIdx.x;
  ushort4 g[20];
  gather_regs(g, senders, receivers, nodes, efeat, tile * MB, tid);

  while (tile < NT) {
    const int e0 = tile * MB;
    write_xs(xs, g, tid);
    __syncthreads();                                   // (A) xs ready

    // q-GEMM: Wq streamed from L2 (issued BEFORE prefetch gathers)
    f32x4 aq[4][2] = {};
#pragma unroll 2
    for (int ks = 0; ks < 10; ++ks) {
      short8 Q0 = *reinterpret_cast<const short8*>(Wqt + n0 * IN_DIM + ks * 32 + lg * 8);
      short8 Q1 = *reinterpret_cast<const short8*>(Wqt + n1 * IN_DIM + ks * 32 + lg * 8);
      short8 A[4];
#pragma unroll
      for (int mt = 0; mt < 4; ++mt)
        A[mt] = *reinterpret_cast<const short8*>(&xs[mt * 16 + lr][ks * 32 + lg * 8]);
#pragma unroll
      for (int mt = 0; mt < 4; ++mt) {
        aq[mt][0] = __builtin_amdgcn_mfma_f32_16x16x32_bf16(A[mt], Q0, aq[mt][0], 0, 0, 0);
        aq[mt][1] = __builtin_amdgcn_mfma_f32_16x16x32_bf16(A[mt], Q1, aq[mt][1], 0, 0, 0);
      }
    }
#pragma unroll
    for (int mt = 0; mt < 4; ++mt)
#pragma unroll
      for (int r = 0; r < 4; ++r) {
        int row = mt * 16 + lg * 4 + r;
        queries[(size_t)(e0 + row) * D + n0] = f2b(aq[mt][0][r] + bq0);
        queries[(size_t)(e0 + row) * D + n1] = f2b(aq[mt][1][r] + bq1);
      }

    // prefetch next tile's gathers
    const int nxt = tile + PGRID;
    if (nxt < NT)
      gather_regs(g, senders, receivers, nodes, efeat, nxt * MB, tid);

    // h-GEMM: weights from registers — zero VMEM
    f32x4 ah[4][2] = {};
#pragma unroll
    for (int ks = 0; ks < 10; ++ks) {
      short8 A[4];
#pragma unroll
      for (int mt = 0; mt < 4; ++mt)
        A[mt] = *reinterpret_cast<const short8*>(&xs[mt * 16 + lr][ks * 32 + lg * 8]);
#pragma unroll
      for (int mt = 0; mt < 4; ++mt) {
        ah[mt][0] = __builtin_amdgcn_mfma_f32_16x16x32_bf16(A[mt], B1r[ks][0], ah[mt][0], 0, 0, 0);
        ah[mt][1] = __builtin_amdgcn_mfma_f32_16x16x32_bf16(A[mt], B1r[ks][1], ah[mt][1], 0, 0, 0);
      }
    }

    // relu + fused LN/dot partials (16-lane reduce: each col once per group)
#pragma unroll
    for (int mt = 0; mt < 4; ++mt)
#pragma unroll
      for (int r = 0; r < 4; ++r) {
        float h0 = fmaxf(ah[mt][0][r] + b1a, 0.f);
        float h1 = fmaxf(ah[mt][1][r] + b1b, 0.f);
        float s = h0 + h1;
        float q = h0 * h0 + h1 * h1;
        float t = h0 * wg0 + h1 * wg1;
#pragma unroll
        for (int off = 1; off < 16; off <<= 1) {
          s += __shfl_xor(s, off);
          q += __shfl_xor(q, off);
          t += __shfl_xor(t, off);
        }
        if (lr == mt * 4 + r) {
          int row = mt * 16 + lg * 4 + r;
          red[row][w][0] = s;
          red[row][w][1] = q;
          red[row][w][2] = t;
        }
      }
    __syncthreads();                                   // (B) red ready
    if (tid < MB) {
      float s = red[tid][0][0] + red[tid][1][0] + red[tid][2][0] + red[tid][3][0];
      float q = red[tid][0][1] + red[tid][1][1] + red[tid][2][1] + red[tid][3][1];
      float t = red[tid][0][2] + red[tid][1][2] + red[tid][2][2] + red[tid][3][2];
      float mu = s * (1.f / 128.f);
      float var = fmaxf(q * (1.f / 128.f) - mu * mu, 0.f);
      float rs = rsqrtf(var + 1e-5f);
      float logit = fmaxf(rs * (t - mu * S1) + B2t, 0.f);
      logits[e0 + tid] = logit;
      atomicMax((int*)&seg_max[receivers[e0 + tid]], __float_as_int(logit));
    }
    tile = nxt;
  }
}

// ---------------- counting sort by receiver ---------------------------------
__global__ __launch_bounds__(256) void k_hist(
    const int* __restrict__ receivers, int* __restrict__ deg)
{
  int e = blockIdx.x * 256 + threadIdx.x;
  if (e < NE) atomicAdd(&deg[receivers[e]], 1);
}

__global__ __launch_bounds__(256) void k_scan1(
    const int* __restrict__ deg, int* __restrict__ bsum)
{
  __shared__ int buf[256];
  int i = blockIdx.x * 256 + threadIdx.x;
  int v = (i < NN) ? deg[i] : 0;
  buf[threadIdx.x] = v;
  __syncthreads();
  for (int off = 128; off > 0; off >>= 1) {
    if (threadIdx.x < off) buf[threadIdx.x] += buf[threadIdx.x + off];
    __syncthreads();
  }
  if (threadIdx.x == 0) bsum[blockIdx.x] = buf[0];
}

__global__ __launch_bounds__(256) void k_scan2(
    const int* __restrict__ bsum, int* __restrict__ bpre, int* __restrict__ offs)
{
  __shared__ int buf[256];
  int t = threadIdx.x;
  int v = (t < NB) ? bsum[t] : 0;
  buf[t] = v;
  __syncthreads();
  for (int off = 1; off < 256; off <<= 1) {
    int x = (t >= off) ? buf[t - off] : 0;
    __syncthreads();
    buf[t] += x;
    __syncthreads();
  }
  if (t < NB) bpre[t] = buf[t] - v;          // exclusive
  if (t == 0) offs[NN] = NE;                  // sentinel
}

__global__ __launch_bounds__(256) void k_scan3(
    const int* __restrict__ deg, const int* __restrict__ bpre,
    int* __restrict__ offs, int* __restrict__ cursor)
{
  __shared__ int buf[256];
  int t = threadIdx.x;
  int i = blockIdx.x * 256 + t;
  int v = (i < NN) ? deg[i] : 0;
  buf[t] = v;
  __syncthreads();
  for (int off = 1; off < 256; off <<= 1) {
    int x = (t >= off) ? buf[t - off] : 0;
    __syncthreads();
    buf[t] += x;
    __syncthreads();
  }
  if (i < NN) {
    int o = bpre[blockIdx.x] + buf[t] - v;
    offs[i] = o;
    cursor[i] = o;
  }
}

__global__ __launch_bounds__(256) void k_bucket(
    const int* __restrict__ receivers, int* __restrict__ cursor,
    int* __restrict__ ebuf)
{
  int e = blockIdx.x * 256 + threadIdx.x;
  if (e < NE) {
    int pos = atomicAdd(&cursor[receivers[e]], 1);
    ebuf[pos] = e;
  }
}

// ---------------- gather-side output: one wave per node, no atomics ---------
__global__ __launch_bounds__(256) void k_out(
    const int* __restrict__ offs, const int* __restrict__ ebuf,
    const float* __restrict__ logits, const float* __restrict__ seg_max,
    const ushort* __restrict__ queries, float* __restrict__ out)
{
  int node = blockIdx.x * 4 + (threadIdx.x >> 6);
  if (node >= NN) return;
  const int l = threadIdx.x & 63;
  const int beg = offs[node], end = offs[node + 1];
  const float smax = seg_max[node];
  float a0 = 0.f, a1 = 0.f, den = 0.f;
  for (int i = beg; i < end; ++i) {
    int e = ebuf[i];
    float ex = expf(logits[e] - smax);
    ushort2 q = *reinterpret_cast<const ushort2*>(queries + (size_t)e * D + 2 * l);
    a0 = fmaf(ex, b2f(q.x), a0);
    a1 = fmaf(ex, b2f(q.y), a1);
    den += ex;
  }
  float inv = 1.f / (den + 1e-10f);
  float v0 = a0 * inv, v1 = a1 * inv;
  v0 = v0 > 0.f ? v0 : 0.01f * v0;
  v1 = v1 > 0.f ? v1 : 0.01f * v1;
  *reinterpret_cast<float2*>(out + (size_t)node * D + 2 * l) = make_float2(v0, v1);
}

extern "C" void kernel_launch(void* const* d_in, const int* in_sizes, int n_in,
                              void* d_out, int out_size, void* d_ws, size_t ws_size,
                              hipStream_t stream) {
  const float* nodes  = (const float*)d_in[0];
  const int*   eidx   = (const int*)d_in[1];
  const float* efeat  = (const float*)d_in[2];
  const float* Wq     = (const float*)d_in[3];
  const float* bq     = (const float*)d_in[4];
  const float* W1     = (const float*)d_in[5];
  const float* b1     = (const float*)d_in[6];
  const float* gamma_ = (const float*)d_in[7];
  const float* beta_  = (const float*)d_in[8];
  const float* W2     = (const float*)d_in[9];
  const float* b2     = (const float*)d_in[10];
  const int* senders   = eidx;
  const int* receivers = eidx + NE;

  // ws layout
  float* ws       = (float*)d_ws;
  float* logits   = ws;                      // NE f32
  float* seg_max  = ws + NE;                 // NN f32
  int*   deg      = (int*)(seg_max + NN);    // NN
  int*   offs     = deg + NN;                // NN+1
  int*   cursor   = offs + NN + 1;           // NN
  int*   bsum     = cursor + NN;             // 256
  int*   bpre     = bsum + 256;              // 256
  int*   ebuf     = bpre + 256;              // NE
  ushort* Wqt     = (ushort*)(ebuf + NE);    // 128*320
  ushort* W1t     = Wqt + D * IN_DIM;        // 128*320
  ushort* queries = W1t + D * IN_DIM;        // NE*128 bf16

  hipMemsetAsync(seg_max, 0, NN * sizeof(float), stream);
  hipMemsetAsync(deg, 0, NN * sizeof(int), stream);

  k_wconv<<<(D * IN_DIM + 255) / 256, 256, 0, stream>>>(Wq, W1, Wqt, W1t);

  // counting sort (independent of k_fused)
  k_hist<<<(NE + 255) / 256, 256, 0, stream>>>(receivers, deg);
  k_scan1<<<NB, 256, 0, stream>>>(deg, bsum);
  k_scan2<<<1, 256, 0, stream>>>(bsum, bpre, offs);
  k_scan3<<<NB, 256, 0, stream>>>(deg, bpre, offs, cursor);
  k_bucket<<<(NE + 255) / 256, 256, 0, stream>>>(receivers, cursor, ebuf);

  // queries + logits + seg_max
  k_fused<<<PGRID, 256, 0, stream>>>(nodes, senders, receivers, efeat,
                                     Wqt, bq, W1t, b1, gamma_, beta_, W2, b2,
                                     queries, logits, seg_max);

  // gather-side softmax + weighted sum + leaky relu
  k_out<<<(NN + 3) / 4, 256, 0, stream>>>(offs, ebuf, logits, seg_max,
                                          queries, (float*)d_out);
}